// Round 7
// baseline (251.161 us; speedup 1.0000x reference)
//
#include <hip/hip_runtime.h>
#include <cstdint>
#include <cstddef>

#define DEVI __device__ __forceinline__

typedef short    shortx8 __attribute__((ext_vector_type(8)));
typedef short    shortx4 __attribute__((ext_vector_type(4)));
typedef short    shortx2 __attribute__((ext_vector_type(2)));
typedef __bf16   bf16x8  __attribute__((ext_vector_type(8)));
typedef float    floatx4 __attribute__((ext_vector_type(4)));

DEVI unsigned short f2b(float f) {
    union { float f; unsigned u; } a; a.f = f;
    unsigned r = a.u + 0x7fffu + ((a.u >> 16) & 1u);
    return (unsigned short)(r >> 16);
}
DEVI float b2f(unsigned short u) {
    union { unsigned u; float f; } a; a.u = ((unsigned)u) << 16;
    return a.f;
}

DEVI floatx4 mfma_bf16(bf16x8 a, bf16x8 b, floatx4 c) {
    return __builtin_amdgcn_mfma_f32_16x16x32_bf16(a, b, c, 0, 0, 0);
}

DEVI void glds16(const ushort* g, ushort* l) {
    __builtin_amdgcn_global_load_lds(
        (const __attribute__((address_space(1))) void*)g,
        (__attribute__((address_space(3))) void*)l, 16, 0, 0);
}

// ---------------- fused prep: x->bf16, W transposes, bias pack ----------------
__global__ void k_prep(const float* __restrict__ x, ushort* __restrict__ xb,
                       const float* __restrict__ Wq, const float* __restrict__ Wk,
                       const float* __restrict__ Wv, const float* __restrict__ Wo,
                       ushort* __restrict__ Wt, ushort* __restrict__ Wot,
                       const float* __restrict__ bq, const float* __restrict__ bk,
                       const float* __restrict__ bv, float* __restrict__ bqkv) {
    __shared__ float tile[64][65];
    const int bid = blockIdx.x, t = threadIdx.x;
    if (bid < 6144) {                      // x -> bf16
        size_t i = ((size_t)bid * 256 + t) * 8;
        float4 v0 = *(const float4*)(x + i);
        float4 v1 = *(const float4*)(x + i + 4);
        shortx8 o;
        o[0] = (short)f2b(v0.x); o[1] = (short)f2b(v0.y);
        o[2] = (short)f2b(v0.z); o[3] = (short)f2b(v0.w);
        o[4] = (short)f2b(v1.x); o[5] = (short)f2b(v1.y);
        o[6] = (short)f2b(v1.z); o[7] = (short)f2b(v1.w);
        *(shortx8*)(xb + i) = o;
    } else if (bid < 6720) {               // W [in][out] fp32 -> [out][in] bf16
        int pid = bid - 6144;
        int zi = pid / 144, rem = pid % 144;
        const float* W = (zi == 0) ? Wq : (zi == 1) ? Wk : (zi == 2) ? Wv : Wo;
        const int i0 = (rem / 12) * 64, j0 = (rem % 12) * 64;
        const int c = t & 63, r4 = t >> 6;
        for (int rr = r4; rr < 64; rr += 4)
            tile[rr][c] = W[(size_t)(i0 + rr) * 768 + j0 + c];
        __syncthreads();
        ushort* dst = (zi < 3) ? (Wt + (size_t)(zi * 768) * 768) : Wot;
        for (int jj = r4; jj < 64; jj += 4)
            dst[(size_t)(j0 + jj) * 768 + i0 + c] = f2b(tile[c][jj]);
    } else {                               // bias pack
        int j = (bid - 6720) * 256 + t;
        if (j < 2304) {
            const float* src = (j < 768) ? bq : (j < 1536) ? bk : bv;
            bqkv[j] = src[j % 768];
        }
    }
}

// ---------------- main GEMM: BK=64, XOR chunk swizzle + locality swizzle ------
// (FROZEN since round 4 — at the m97-structure ceiling for this shape.)
// LDS logical As[row][k0..63]; element (r,k) at r*64 + ((k>>3)^(r&7))*8 + (k&7).
// Staging: glds16 #i covers rows +i*8..+i*8+8, lane -> (row=lane>>3, slot=lane&7),
// source column permuted per lane so coalescing (full 128B rows) is preserved.
// Block-index swizzle: XCD chunking (m204) + 8-m-block band traversal.
template <int MODE>
__global__ __launch_bounds__(256, 4) void k_gemm(
    const ushort* __restrict__ A, const ushort* __restrict__ Bt,
    const float* __restrict__ bias, void* __restrict__ Cout, int Ncols) {
    constexpr int K = 768;
    constexpr int GY = (MODE == 0) ? 18 : 6;   // grid.y (must match launch)
    constexpr int NWG = 128 * GY;
    __shared__ ushort As[128 * 64];
    __shared__ ushort Bs[128 * 64];

    const int lin  = blockIdx.y * 128 + blockIdx.x;       // dispatch order
    const int wg   = (lin & 7) * (NWG / 8) + (lin >> 3);  // XCD-contiguous
    const int band = wg / (8 * GY);                       // super-row of 8 m-blocks
    const int rem  = wg % (8 * GY);
    const int m0 = (band * 8 + (rem & 7)) * 128;
    const int n0 = (rem >> 3) * 128;

    const int tid = threadIdx.x;
    const int w = tid >> 6, lane = tid & 63;

    const int lr = lane >> 3;                    // row within 8-row slab
    const int lc = ((lane & 7) ^ lr) * 8;        // swizzled source chunk
    const ushort* aBase = A  + (size_t)(m0 + w * 32 + lr) * K + lc;
    const ushort* bBase = Bt + (size_t)(n0 + w * 32 + lr) * K + lc;
    ushort* aL = As + (w * 32) * 64;             // wave-uniform LDS bases
    ushort* bL = Bs + (w * 32) * 64;

    const int rBase = (w >> 1) * 64;
    const int nBase = (w & 1) * 64;
    const int fr = lane & 15;
    const int q4 = lane >> 4;

    floatx4 acc[4][4] = {};

    for (int k0 = 0; k0 < K; k0 += 64) {
#pragma unroll
        for (int i = 0; i < 4; ++i) glds16(aBase + i * (8 * K) + k0, aL + i * (8 * 64));
#pragma unroll
        for (int i = 0; i < 4; ++i) glds16(bBase + i * (8 * K) + k0, bL + i * (8 * 64));
        __syncthreads();
#pragma unroll
        for (int kc = 0; kc < 2; ++kc) {
            const int off = ((kc * 4 + q4) ^ (fr & 7)) * 8;
            bf16x8 af[4], bf[4];
#pragma unroll
            for (int rt = 0; rt < 4; ++rt)
                af[rt] = *(const bf16x8*)(As + (rBase + rt * 16 + fr) * 64 + off);
#pragma unroll
            for (int nt = 0; nt < 4; ++nt)
                bf[nt] = *(const bf16x8*)(Bs + (nBase + nt * 16 + fr) * 64 + off);
#pragma unroll
            for (int rt = 0; rt < 4; ++rt)
#pragma unroll
                for (int nt = 0; nt < 4; ++nt)
                    acc[rt][nt] = mfma_bf16(af[rt], bf[nt], acc[rt][nt]);
        }
        __syncthreads();
    }

#pragma unroll
    for (int rt = 0; rt < 4; ++rt) {
#pragma unroll
        for (int nt = 0; nt < 4; ++nt) {
#pragma unroll
            for (int r = 0; r < 4; ++r) {
                int m = m0 + rBase + rt * 16 + q4 * 4 + r;
                int n = n0 + nBase + nt * 16 + fr;
                float v = acc[rt][nt][r] + bias[n];
                if (MODE == 0) {
                    if (n < 1536) v = (v > 0.f) ? (v + 1.f) : __expf(v);  // phi
                    ((ushort*)Cout)[(size_t)m * Ncols + n] = f2b(v);
                } else {
                    ((float*)Cout)[(size_t)m * Ncols + n] = v;
                }
            }
        }
    }
}

// ---------------- kv + ksum via MFMA: 256 rows/block, dbuf + early-issue ------
// (round-6 version, kept)
#define KV_LOAD(rr, r)  do {                                          \
    const ushort* kp = base + (size_t)((rr) * 64 + n_ld) * 2304;      \
    r[0] = *(const shortx8*)(kp);                                     \
    r[1] = *(const shortx8*)(kp + 8);                                 \
    r[2] = *(const shortx8*)(kp + 768);                               \
    r[3] = *(const shortx8*)(kp + 776); } while (0)

#define KV_STORE(buf, r) do {                                         \
    union { shortx8 v8; shortx2 v2[4]; } u0, u1, u2, u3;              \
    u0.v8 = r[0]; u1.v8 = r[1]; u2.v8 = r[2]; u3.v8 = r[3];           \
    ushort* kd = kS[buf] + n_ld * 70 + c16;                           \
    ushort* vd = vS[buf] + n_ld * 70 + c16;                           \
    _Pragma("unroll")                                                 \
    for (int i = 0; i < 4; ++i) {                                     \
        *(shortx2*)(kd + 2 * i)     = u0.v2[i];                       \
        *(shortx2*)(kd + 8 + 2 * i) = u1.v2[i];                       \
        *(shortx2*)(vd + 2 * i)     = u2.v2[i];                       \
        *(shortx2*)(vd + 8 + 2 * i) = u3.v2[i]; } } while (0)

__global__ __launch_bounds__(256) void k_kv(const ushort* __restrict__ QKV,
                                            float* __restrict__ kvp) {
    const int bh = blockIdx.x, s = blockIdx.y;           // s in [0,16)
    const int bb = bh / 12, head = bh % 12;
    __shared__ ushort kS[2][64 * 70];
    __shared__ ushort vS[2][64 * 70];
    const int t = threadIdx.x, w = t >> 6, lane = t & 63;
    const int fr = lane & 15, fk = (lane >> 4) * 8;

    floatx4 acc[5] = {};
    const int n_ld = t >> 2, c16 = (t & 3) * 16;
    const ushort* base = QKV + (size_t)(bb * 4096 + s * 256) * 2304 + 768 + head * 64 + c16;

    union { bf16x8 v; ushort u[8]; } ones;
    {
        ushort ov = (fr == 0) ? (ushort)0x3F80 : (ushort)0;
#pragma unroll
        for (int i = 0; i < 8; ++i) ones.u[i] = ov;
    }

    shortx8 rA[4], rB[4];
    KV_LOAD(0, rA);
    KV_STORE(0, rA);

#pragma unroll
    for (int rr = 0; rr < 4; ++rr) {
        __syncthreads();                   // prior ds_writes visible; prior reads done
        if (rr == 0)      KV_LOAD(1, rB);  // early-issue: latency hides under MFMA
        else if (rr == 1) KV_LOAD(2, rA);
        else if (rr == 2) KV_LOAD(3, rB);
        const int buf = rr & 1;
#pragma unroll
        for (int kl = 0; kl < 64; kl += 32) {
            union { bf16x8 v; ushort u[8]; } bfr, afr[4];
#pragma unroll
            for (int i = 0; i < 8; ++i) {
                int n = kl + fk + i;
                bfr.u[i] = kS[buf][n * 70 + w * 16 + fr];
#pragma unroll
                for (int mt = 0; mt < 4; ++mt)
                    afr[mt].u[i] = vS[buf][n * 70 + mt * 16 + fr];
            }
#pragma unroll
            for (int mt = 0; mt < 4; ++mt)
                acc[mt] = mfma_bf16(afr[mt].v, bfr.v, acc[mt]);
            acc[4] = mfma_bf16(ones.v, bfr.v, acc[4]);
        }
        if (rr == 0)      KV_STORE(1, rB); // write other buffer (readers done at rr-1)
        else if (rr == 1) KV_STORE(0, rA);
        else if (rr == 2) KV_STORE(1, rB);
    }

    float* dst = kvp + ((size_t)bh * 16 + s) * (65 * 64);
#pragma unroll
    for (int mt = 0; mt < 4; ++mt)
#pragma unroll
        for (int r = 0; r < 4; ++r)
            dst[(mt * 16 + (lane >> 4) * 4 + r) * 64 + w * 16 + fr] = acc[mt][r];
    if (lane < 16) dst[64 * 64 + w * 16 + lane] = acc[4][0];
}

// reduce 16 partials, emit bf16: kvb [48][65][64]
__global__ void k_kvred(const float* __restrict__ kvp, ushort* __restrict__ kvb) {
    int t4 = (blockIdx.x * 256 + threadIdx.x) * 4;   // 195*256*4 == 199680
    int bh = t4 / 4160, rem = t4 % 4160;
    const float* p = kvp + (size_t)bh * 16 * 4160 + rem;
    float4 sum = {0.f, 0.f, 0.f, 0.f};
    for (int i = 0; i < 16; ++i) {
        float4 a = *(const float4*)(p + (size_t)i * 4160);
        sum.x += a.x; sum.y += a.y; sum.z += a.z; sum.w += a.w;
    }
    shortx4 o;
    o[0] = (short)f2b(sum.x); o[1] = (short)f2b(sum.y);
    o[2] = (short)f2b(sum.z); o[3] = (short)f2b(sum.w);
    *(shortx4*)(kvb + t4) = o;
}

// ------- fused num + z + normed + output GEMM (k_num + k_gemm<1> merged) ------
// Grid (128, 6): block computes C[m0..m0+128][n0..n0+128] = sum over heads h of
// normed_h[128x64] @ WotT_h[64x128] + bo, where normed_h is computed IN-KERNEL:
//   per head-step: {glds16 Bs(Wot) || stage q,kvT -> bar -> num MFMA (k_num
//   inner, acc2[2][5]) -> dnm exchange -> bar -> normed=num*z, f2b, write into
//   the q LDS buffer (dead after num MFMA) -> bar -> 16 main MFMA -> bar}.
// Eliminates the normed global round-trip (50 MB) and one dispatch. Summation
// order identical to the split path (h ascending, kc inner, same f2b points).
// LDS 46.8 KB -> 3 blocks/CU. Band swizzle keeps the 6 n-blocks of each m
// co-resident so the x6 Q re-reads stay L2-hot.
__global__ __launch_bounds__(256, 3) void k_fng(
    const ushort* __restrict__ QKV, const ushort* __restrict__ kvb,
    const ushort* __restrict__ Wot, const float* __restrict__ bias,
    float* __restrict__ Cout) {
    constexpr int GY = 6;
    constexpr int NWG = 128 * GY;
    __shared__ ushort qsh[128 * 72];     // q, then normed (reused per head)
    __shared__ ushort kvT[80 * 72];
    __shared__ ushort Bs[128 * 64];      // XOR-chunk-swizzled (glds16 staged)
    __shared__ float dnm[128];

    const int lin  = blockIdx.y * 128 + blockIdx.x;
    const int wg   = (lin & 7) * (NWG / 8) + (lin >> 3);  // XCD-contiguous
    const int band = wg / (8 * GY);
    const int rem  = wg % (8 * GY);
    const int m0 = (band * 8 + (rem & 7)) * 128;
    const int n0 = (rem >> 3) * 128;

    const int t = threadIdx.x, w = t >> 6, lane = t & 63;
    const int fr = lane & 15, q4 = lane >> 4, fk = q4 * 8;
    const int lr = lane >> 3, lc = ((lane & 7) ^ lr) * 8;
    const int rBase = (w >> 1) * 64, nBase = (w & 1) * 64;

    const ushort* bgBase = Wot + (size_t)(n0 + w * 32 + lr) * 768 + lc;
    ushort* bL = Bs + (w * 32) * 64;
    const int srow = t >> 3, sc8 = (t & 7) * 8;   // q / kvT staging coords
    const ushort* kvbase = kvb + (size_t)(m0 >> 12) * 12 * 4160;
    const ushort* qgBase = QKV + (size_t)m0 * 2304;

    for (int idx = t; idx < 15 * 72; idx += 256) kvT[65 * 72 + idx] = 0;

    floatx4 acc[4][4] = {};

    for (int h = 0; h < 12; ++h) {
        // ---- stage: Bs (async glds16) || kvT, q (regs -> LDS) ----
#pragma unroll
        for (int i = 0; i < 4; ++i)
            glds16(bgBase + i * (8 * 768) + h * 64, bL + i * 512);
        {
            const ushort* kvbb = kvbase + h * 4160;
            for (int r0 = srow; r0 < 65; r0 += 32)
                *(shortx8*)(kvT + r0 * 72 + sc8) = *(const shortx8*)(kvbb + r0 * 64 + sc8);
        }
        {
            const ushort* qg = qgBase + h * 64;
#pragma unroll
            for (int i = 0; i < 4; ++i) {
                shortx8 v = *(const shortx8*)(qg + (size_t)(i * 32 + srow) * 2304 + sc8);
                *(shortx8*)(qsh + (i * 32 + srow) * 72 + sc8) = v;
            }
        }
        __syncthreads();

        // ---- num MFMA (k_num inner, verbatim) ----
        floatx4 acc2[2][5] = {};
#pragma unroll
        for (int kc = 0; kc < 2; ++kc) {
            bf16x8 a[2], b[5];
#pragma unroll
            for (int rt = 0; rt < 2; ++rt)
                a[rt] = *(const bf16x8*)(qsh + (w * 32 + rt * 16 + fr) * 72 + kc * 32 + fk);
#pragma unroll
            for (int nt = 0; nt < 5; ++nt)
                b[nt] = *(const bf16x8*)(kvT + (nt * 16 + fr) * 72 + kc * 32 + fk);
#pragma unroll
            for (int rt = 0; rt < 2; ++rt)
#pragma unroll
                for (int nt = 0; nt < 5; ++nt)
                    acc2[rt][nt] = mfma_bf16(a[rt], b[nt], acc2[rt][nt]);
        }
        if (fr == 0) {
#pragma unroll
            for (int rt = 0; rt < 2; ++rt)
#pragma unroll
                for (int r = 0; r < 4; ++r)
                    dnm[w * 32 + rt * 16 + q4 * 4 + r] = acc2[rt][4][r];
        }
        __syncthreads();

        // ---- normalize -> write normed (bf16) into qsh (q is dead) ----
#pragma unroll
        for (int rt = 0; rt < 2; ++rt) {
#pragma unroll
            for (int r = 0; r < 4; ++r) {
                int ml = w * 32 + rt * 16 + q4 * 4 + r;
                float z = 1.f / dnm[ml];
#pragma unroll
                for (int nt = 0; nt < 4; ++nt)
                    qsh[ml * 72 + nt * 16 + fr] = f2b(acc2[rt][nt][r] * z);
            }
        }
        __syncthreads();

        // ---- main MFMA: C += normed_h @ WotT_h ----
#pragma unroll
        for (int kc = 0; kc < 2; ++kc) {
            const int off = ((kc * 4 + q4) ^ (fr & 7)) * 8;
            bf16x8 af[4], bf[4];
#pragma unroll
            for (int rt = 0; rt < 4; ++rt)
                af[rt] = *(const bf16x8*)(qsh + (rBase + rt * 16 + fr) * 72 + kc * 32 + fk);
#pragma unroll
            for (int nt = 0; nt < 4; ++nt)
                bf[nt] = *(const bf16x8*)(Bs + (nBase + nt * 16 + fr) * 64 + off);
#pragma unroll
            for (int rt = 0; rt < 4; ++rt)
#pragma unroll
                for (int nt = 0; nt < 4; ++nt)
                    acc[rt][nt] = mfma_bf16(af[rt], bf[nt], acc[rt][nt]);
        }
        __syncthreads();
    }

    // ---- epilogue: f32 + bias ----
#pragma unroll
    for (int rt = 0; rt < 4; ++rt) {
#pragma unroll
        for (int nt = 0; nt < 4; ++nt) {
#pragma unroll
            for (int r = 0; r < 4; ++r) {
                int m = m0 + rBase + rt * 16 + q4 * 4 + r;
                int n = n0 + nBase + nt * 16 + fr;
                Cout[(size_t)m * 768 + n] = acc[rt][nt][r] + bias[n];
            }
        }
    }
}

// ---------------- launch ----------------
// Workspace: kvp (12,779,520 B f32 partials) aliases the Xb slot (Xb dead after
// gemm<0>; kvred drains kvp into kvb before any reuse). `normed` no longer
// exists — k_fng computes it in-LDS.
extern "C" void kernel_launch(void* const* d_in, const int* in_sizes, int n_in,
                              void* d_out, int out_size, void* d_ws, size_t ws_size,
                              hipStream_t stream) {
    const float* x  = (const float*)d_in[0];
    const float* Wq = (const float*)d_in[1];
    const float* bq = (const float*)d_in[2];
    const float* Wk = (const float*)d_in[3];
    const float* bk = (const float*)d_in[4];
    const float* Wv = (const float*)d_in[5];
    const float* bv = (const float*)d_in[6];
    const float* Wo = (const float*)d_in[7];
    const float* bo = (const float*)d_in[8];

    char* ws = (char*)d_ws;
    ushort* Xb   = (ushort*)(ws);                 // 25,165,824 B (reused: kvp)
    ushort* Wt   = (ushort*)(ws + 25165824);      //  3,538,944 B
    ushort* Wot  = (ushort*)(ws + 28704768);      //  1,179,648 B
    float*  bqkv = (float*)(ws + 29884416);       //      9,216 B
    ushort* QKV  = (ushort*)(ws + 29893632);      // 75,497,472 B
    ushort* kvb  = (ushort*)(ws + 111780864);     //    399,360 B
    float*  kvp  = (float*)(ws);                  // 12,779,520 B (aliases Xb)

    k_prep <<<dim3(6729),      256, 0, stream>>>(x, Xb, Wq, Wk, Wv, Wo, Wt, Wot,
                                                 bq, bk, bv, bqkv);
    k_gemm<0><<<dim3(128, 18), 256, 0, stream>>>(Xb, Wt, bqkv, (void*)QKV, 2304);
    k_kv   <<<dim3(48, 16),    256, 0, stream>>>(QKV, kvp);
    k_kvred<<<dim3(195),       256, 0, stream>>>(kvp, kvb);
    k_fng  <<<dim3(128, 6),    256, 0, stream>>>(QKV, kvb, Wot, bo, (float*)d_out);
}

// Round 9
// 234.015 us; speedup vs baseline: 1.0733x; 1.0733x over previous
//
#include <hip/hip_runtime.h>
#include <cstdint>
#include <cstddef>

#define DEVI __device__ __forceinline__

typedef short    shortx8 __attribute__((ext_vector_type(8)));
typedef short    shortx4 __attribute__((ext_vector_type(4)));
typedef short    shortx2 __attribute__((ext_vector_type(2)));
typedef __bf16   bf16x8  __attribute__((ext_vector_type(8)));
typedef float    floatx4 __attribute__((ext_vector_type(4)));

DEVI unsigned short f2b(float f) {
    union { float f; unsigned u; } a; a.f = f;
    unsigned r = a.u + 0x7fffu + ((a.u >> 16) & 1u);
    return (unsigned short)(r >> 16);
}
DEVI float b2f(unsigned short u) {
    union { unsigned u; float f; } a; a.u = ((unsigned)u) << 16;
    return a.f;
}

DEVI floatx4 mfma_bf16(bf16x8 a, bf16x8 b, floatx4 c) {
    return __builtin_amdgcn_mfma_f32_16x16x32_bf16(a, b, c, 0, 0, 0);
}

DEVI void glds16(const ushort* g, ushort* l) {
    __builtin_amdgcn_global_load_lds(
        (const __attribute__((address_space(1))) void*)g,
        (__attribute__((address_space(3))) void*)l, 16, 0, 0);
}

// ---------------- fused prep: x->bf16, W transposes, bias pack ----------------
__global__ void k_prep(const float* __restrict__ x, ushort* __restrict__ xb,
                       const float* __restrict__ Wq, const float* __restrict__ Wk,
                       const float* __restrict__ Wv, const float* __restrict__ Wo,
                       ushort* __restrict__ Wt, ushort* __restrict__ Wot,
                       const float* __restrict__ bq, const float* __restrict__ bk,
                       const float* __restrict__ bv, float* __restrict__ bqkv) {
    __shared__ float tile[64][65];
    const int bid = blockIdx.x, t = threadIdx.x;
    if (bid < 6144) {                      // x -> bf16
        size_t i = ((size_t)bid * 256 + t) * 8;
        float4 v0 = *(const float4*)(x + i);
        float4 v1 = *(const float4*)(x + i + 4);
        shortx8 o;
        o[0] = (short)f2b(v0.x); o[1] = (short)f2b(v0.y);
        o[2] = (short)f2b(v0.z); o[3] = (short)f2b(v0.w);
        o[4] = (short)f2b(v1.x); o[5] = (short)f2b(v1.y);
        o[6] = (short)f2b(v1.z); o[7] = (short)f2b(v1.w);
        *(shortx8*)(xb + i) = o;
    } else if (bid < 6720) {               // W [in][out] fp32 -> [out][in] bf16
        int pid = bid - 6144;
        int zi = pid / 144, rem = pid % 144;
        const float* W = (zi == 0) ? Wq : (zi == 1) ? Wk : (zi == 2) ? Wv : Wo;
        const int i0 = (rem / 12) * 64, j0 = (rem % 12) * 64;
        const int c = t & 63, r4 = t >> 6;
        for (int rr = r4; rr < 64; rr += 4)
            tile[rr][c] = W[(size_t)(i0 + rr) * 768 + j0 + c];
        __syncthreads();
        ushort* dst = (zi < 3) ? (Wt + (size_t)(zi * 768) * 768) : Wot;
        for (int jj = r4; jj < 64; jj += 4)
            dst[(size_t)(j0 + jj) * 768 + i0 + c] = f2b(tile[c][jj]);
    } else {                               // bias pack
        int j = (bid - 6720) * 256 + t;
        if (j < 2304) {
            const float* src = (j < 768) ? bq : (j < 1536) ? bk : bv;
            bqkv[j] = src[j % 768];
        }
    }
}

// ---------------- main GEMM: BK=64, XOR chunk swizzle + locality swizzle ------
// (FROZEN since round 4 — at the m97-structure ceiling for this shape.)
// LDS logical As[row][k0..63]; element (r,k) at r*64 + ((k>>3)^(r&7))*8 + (k&7).
// Staging: glds16 #i covers rows +i*8..+i*8+8, lane -> (row=lane>>3, slot=lane&7),
// source column permuted per lane so coalescing (full 128B rows) is preserved.
// Block-index swizzle: XCD chunking (m204) + 8-m-block band traversal.
template <int MODE>
__global__ __launch_bounds__(256, 4) void k_gemm(
    const ushort* __restrict__ A, const ushort* __restrict__ Bt,
    const float* __restrict__ bias, void* __restrict__ Cout, int Ncols) {
    constexpr int K = 768;
    constexpr int GY = (MODE == 0) ? 18 : 6;   // grid.y (must match launch)
    constexpr int NWG = 128 * GY;
    __shared__ ushort As[128 * 64];
    __shared__ ushort Bs[128 * 64];

    const int lin  = blockIdx.y * 128 + blockIdx.x;       // dispatch order
    const int wg   = (lin & 7) * (NWG / 8) + (lin >> 3);  // XCD-contiguous
    const int band = wg / (8 * GY);                       // super-row of 8 m-blocks
    const int rem  = wg % (8 * GY);
    const int m0 = (band * 8 + (rem & 7)) * 128;
    const int n0 = (rem >> 3) * 128;

    const int tid = threadIdx.x;
    const int w = tid >> 6, lane = tid & 63;

    const int lr = lane >> 3;                    // row within 8-row slab
    const int lc = ((lane & 7) ^ lr) * 8;        // swizzled source chunk
    const ushort* aBase = A  + (size_t)(m0 + w * 32 + lr) * K + lc;
    const ushort* bBase = Bt + (size_t)(n0 + w * 32 + lr) * K + lc;
    ushort* aL = As + (w * 32) * 64;             // wave-uniform LDS bases
    ushort* bL = Bs + (w * 32) * 64;

    const int rBase = (w >> 1) * 64;
    const int nBase = (w & 1) * 64;
    const int fr = lane & 15;
    const int q4 = lane >> 4;

    floatx4 acc[4][4] = {};

    for (int k0 = 0; k0 < K; k0 += 64) {
#pragma unroll
        for (int i = 0; i < 4; ++i) glds16(aBase + i * (8 * K) + k0, aL + i * (8 * 64));
#pragma unroll
        for (int i = 0; i < 4; ++i) glds16(bBase + i * (8 * K) + k0, bL + i * (8 * 64));
        __syncthreads();
#pragma unroll
        for (int kc = 0; kc < 2; ++kc) {
            const int off = ((kc * 4 + q4) ^ (fr & 7)) * 8;
            bf16x8 af[4], bf[4];
#pragma unroll
            for (int rt = 0; rt < 4; ++rt)
                af[rt] = *(const bf16x8*)(As + (rBase + rt * 16 + fr) * 64 + off);
#pragma unroll
            for (int nt = 0; nt < 4; ++nt)
                bf[nt] = *(const bf16x8*)(Bs + (nBase + nt * 16 + fr) * 64 + off);
#pragma unroll
            for (int rt = 0; rt < 4; ++rt)
#pragma unroll
                for (int nt = 0; nt < 4; ++nt)
                    acc[rt][nt] = mfma_bf16(af[rt], bf[nt], acc[rt][nt]);
        }
        __syncthreads();
    }

#pragma unroll
    for (int rt = 0; rt < 4; ++rt) {
#pragma unroll
        for (int nt = 0; nt < 4; ++nt) {
#pragma unroll
            for (int r = 0; r < 4; ++r) {
                int m = m0 + rBase + rt * 16 + q4 * 4 + r;
                int n = n0 + nBase + nt * 16 + fr;
                float v = acc[rt][nt][r] + bias[n];
                if (MODE == 0) {
                    if (n < 1536) v = (v > 0.f) ? (v + 1.f) : __expf(v);  // phi
                    ((ushort*)Cout)[(size_t)m * Ncols + n] = f2b(v);
                } else {
                    ((float*)Cout)[(size_t)m * Ncols + n] = v;
                }
            }
        }
    }
}

// ---------------- kv + ksum via MFMA (round-4 version, verbatim) --------------
__global__ __launch_bounds__(256) void k_kv(const ushort* __restrict__ QKV,
                                            float* __restrict__ kvp) {
    const int bh = blockIdx.x, s = blockIdx.y;
    const int bb = bh / 12, head = bh % 12;
    __shared__ ushort kS[64 * 70];
    __shared__ ushort vS[64 * 70];
    const int t = threadIdx.x, w = t >> 6, lane = t & 63;
    const int fr = lane & 15, fk = (lane >> 4) * 8;

    floatx4 acc[5] = {};
    const int n_ld = t >> 2, c16 = (t & 3) * 16;
    const ushort* base = QKV + (size_t)(bb * 4096 + s * 512) * 2304 + 768 + head * 64 + c16;

    for (int rr = 0; rr < 8; ++rr) {
        if (rr) __syncthreads();
        {
            const ushort* kp = base + (size_t)(rr * 64 + n_ld) * 2304;
            union { shortx8 v8; shortx2 v2[4]; } k0, k1, v0, v1;
            k0.v8 = *(const shortx8*)(kp);
            k1.v8 = *(const shortx8*)(kp + 8);
            v0.v8 = *(const shortx8*)(kp + 768);
            v1.v8 = *(const shortx8*)(kp + 776);
            ushort* kd = kS + n_ld * 70 + c16;
            ushort* vd = vS + n_ld * 70 + c16;
#pragma unroll
            for (int i = 0; i < 4; ++i) {
                *(shortx2*)(kd + 2 * i)     = k0.v2[i];
                *(shortx2*)(kd + 8 + 2 * i) = k1.v2[i];
                *(shortx2*)(vd + 2 * i)     = v0.v2[i];
                *(shortx2*)(vd + 8 + 2 * i) = v1.v2[i];
            }
        }
        __syncthreads();
#pragma unroll
        for (int kl = 0; kl < 64; kl += 32) {
            union { bf16x8 v; ushort u[8]; } bfr, afr[4];
#pragma unroll
            for (int i = 0; i < 8; ++i) {
                int n = kl + fk + i;
                bfr.u[i] = kS[n * 70 + w * 16 + fr];
#pragma unroll
                for (int mt = 0; mt < 4; ++mt)
                    afr[mt].u[i] = vS[n * 70 + mt * 16 + fr];
            }
            union { bf16x8 v; ushort u[8]; } ones;
            ushort ov = (fr == 0) ? (ushort)0x3F80 : (ushort)0;
#pragma unroll
            for (int i = 0; i < 8; ++i) ones.u[i] = ov;
#pragma unroll
            for (int mt = 0; mt < 4; ++mt)
                acc[mt] = mfma_bf16(afr[mt].v, bfr.v, acc[mt]);
            acc[4] = mfma_bf16(ones.v, bfr.v, acc[4]);
        }
    }

    float* dst = kvp + ((size_t)bh * 8 + s) * (65 * 64);
#pragma unroll
    for (int mt = 0; mt < 4; ++mt)
#pragma unroll
        for (int r = 0; r < 4; ++r)
            dst[(mt * 16 + (lane >> 4) * 4 + r) * 64 + w * 16 + fr] = acc[mt][r];
    if (lane < 16) dst[64 * 64 + w * 16 + lane] = acc[4][0];
}

// ---------------- num + z + normed (MFMA); kvred FUSED into kvT staging -------
// Round-8: kvT is built by summing the 8 f32 partials directly (same i=0..7
// ascending order and same f2b point as the old k_kvred -> bit-identical
// numerics), eliminating the k_kvred dispatch and the kvb round-trip. kvp is
// 6.4 MB -> L3-resident; the per-block 133 KB re-read hits cache.
__global__ __launch_bounds__(256) void k_num(const ushort* __restrict__ QKV,
                                             const float* __restrict__ kvp,
                                             ushort* __restrict__ normed) {
    const int bh = blockIdx.x, l0 = blockIdx.y * 128;
    const int bb = bh / 12, head = bh % 12;
    __shared__ ushort qsh[128 * 72];
    __shared__ ushort kvT[80 * 72];
    __shared__ float dnm[128];
    const int t = threadIdx.x, w = t >> 6, lane = t & 63;

    {
        const float* kvf = kvp + (size_t)bh * 8 * 4160;
        int c4 = (t & 15) * 4;               // 16 thr x float4 = one 64-col row
        for (int r0 = (t >> 4); r0 < 65; r0 += 16) {
            float4 sum = {0.f, 0.f, 0.f, 0.f};
#pragma unroll
            for (int i = 0; i < 8; ++i) {
                float4 a = *(const float4*)(kvf + (size_t)i * 4160 + r0 * 64 + c4);
                sum.x += a.x; sum.y += a.y; sum.z += a.z; sum.w += a.w;
            }
            shortx4 o;
            o[0] = (short)f2b(sum.x); o[1] = (short)f2b(sum.y);
            o[2] = (short)f2b(sum.z); o[3] = (short)f2b(sum.w);
            *(shortx4*)(kvT + r0 * 72 + c4) = o;
        }
    }
    for (int idx = t; idx < 15 * 72; idx += 256) kvT[65 * 72 + idx] = 0;

    const ushort* qg = QKV + (size_t)(bb * 4096 + l0) * 2304 + head * 64;
    {
        int row = t >> 3, c8 = (t & 7) * 8;
#pragma unroll
        for (int i = 0; i < 4; ++i) {
            shortx8 v = *(const shortx8*)(qg + (size_t)(i * 32 + row) * 2304 + c8);
            *(shortx8*)(qsh + (i * 32 + row) * 72 + c8) = v;
        }
    }
    __syncthreads();

    const int fr = lane & 15, fk = (lane >> 4) * 8;
    floatx4 acc[2][5] = {};
#pragma unroll
    for (int kc = 0; kc < 2; ++kc) {
        bf16x8 a[2], b[5];
#pragma unroll
        for (int rt = 0; rt < 2; ++rt)
            a[rt] = *(const bf16x8*)(qsh + (w * 32 + rt * 16 + fr) * 72 + kc * 32 + fk);
#pragma unroll
        for (int nt = 0; nt < 5; ++nt)
            b[nt] = *(const bf16x8*)(kvT + (nt * 16 + fr) * 72 + kc * 32 + fk);
#pragma unroll
        for (int rt = 0; rt < 2; ++rt)
#pragma unroll
            for (int nt = 0; nt < 5; ++nt)
                acc[rt][nt] = mfma_bf16(a[rt], b[nt], acc[rt][nt]);
    }
    if (fr == 0) {
#pragma unroll
        for (int rt = 0; rt < 2; ++rt)
#pragma unroll
            for (int r = 0; r < 4; ++r)
                dnm[w * 32 + rt * 16 + (lane >> 4) * 4 + r] = acc[rt][4][r];
    }
    __syncthreads();
#pragma unroll
    for (int rt = 0; rt < 2; ++rt) {
#pragma unroll
        for (int r = 0; r < 4; ++r) {
            int ml = w * 32 + rt * 16 + (lane >> 4) * 4 + r;
            float z = 1.f / dnm[ml];
            size_t base = (size_t)(bb * 4096 + l0 + ml) * 768 + head * 64;
#pragma unroll
            for (int nt = 0; nt < 4; ++nt)
                normed[base + nt * 16 + fr] = f2b(acc[rt][nt][r] * z);
        }
    }
}

// ---------------- launch ----------------
// 5 dispatches (k_kvred fused into k_num). kvp lives after QKV (no aliasing
// with Xb: k_num reads kvp while writing normed=Xb).
extern "C" void kernel_launch(void* const* d_in, const int* in_sizes, int n_in,
                              void* d_out, int out_size, void* d_ws, size_t ws_size,
                              hipStream_t stream) {
    const float* x  = (const float*)d_in[0];
    const float* Wq = (const float*)d_in[1];
    const float* bq = (const float*)d_in[2];
    const float* Wk = (const float*)d_in[3];
    const float* bk = (const float*)d_in[4];
    const float* Wv = (const float*)d_in[5];
    const float* bv = (const float*)d_in[6];
    const float* Wo = (const float*)d_in[7];
    const float* bo = (const float*)d_in[8];

    char* ws = (char*)d_ws;
    ushort* Xb   = (ushort*)(ws);                 // 25,165,824 B (reused as normed)
    ushort* Wt   = (ushort*)(ws + 25165824);      //  3,538,944 B
    ushort* Wot  = (ushort*)(ws + 28704768);      //  1,179,648 B
    float*  bqkv = (float*)(ws + 29884416);       //      9,216 B
    ushort* QKV  = (ushort*)(ws + 29893632);      // 75,497,472 B
    float*  kvp  = (float*)(ws + 105391104);      //  6,389,760 B (f32 partials)
    ushort* normed = Xb;

    k_prep <<<dim3(6729),      256, 0, stream>>>(x, Xb, Wq, Wk, Wv, Wo, Wt, Wot,
                                                 bq, bk, bv, bqkv);
    k_gemm<0><<<dim3(128, 18), 256, 0, stream>>>(Xb, Wt, bqkv, (void*)QKV, 2304);
    k_kv   <<<dim3(48, 8),     256, 0, stream>>>(QKV, kvp);
    k_num  <<<dim3(48, 32),    256, 0, stream>>>(QKV, kvp, normed);
    k_gemm<1><<<dim3(128, 6),  256, 0, stream>>>(normed, Wot, bo, d_out, 768);
}

// Round 10
// 228.577 us; speedup vs baseline: 1.0988x; 1.0238x over previous
//
#include <hip/hip_runtime.h>
#include <cstdint>
#include <cstddef>

#define DEVI __device__ __forceinline__

typedef short    shortx8 __attribute__((ext_vector_type(8)));
typedef short    shortx4 __attribute__((ext_vector_type(4)));
typedef short    shortx2 __attribute__((ext_vector_type(2)));
typedef __bf16   bf16x8  __attribute__((ext_vector_type(8)));
typedef float    floatx4 __attribute__((ext_vector_type(4)));

DEVI unsigned short f2b(float f) {
    union { float f; unsigned u; } a; a.f = f;
    unsigned r = a.u + 0x7fffu + ((a.u >> 16) & 1u);
    return (unsigned short)(r >> 16);
}
DEVI float b2f(unsigned short u) {
    union { unsigned u; float f; } a; a.u = ((unsigned)u) << 16;
    return a.f;
}

DEVI floatx4 mfma_bf16(bf16x8 a, bf16x8 b, floatx4 c) {
    return __builtin_amdgcn_mfma_f32_16x16x32_bf16(a, b, c, 0, 0, 0);
}

DEVI void glds16(const ushort* g, ushort* l) {
    __builtin_amdgcn_global_load_lds(
        (const __attribute__((address_space(1))) void*)g,
        (__attribute__((address_space(3))) void*)l, 16, 0, 0);
}

// ---------------- fused prep: x->bf16, W transposes, bias pack ----------------
__global__ void k_prep(const float* __restrict__ x, ushort* __restrict__ xb,
                       const float* __restrict__ Wq, const float* __restrict__ Wk,
                       const float* __restrict__ Wv, const float* __restrict__ Wo,
                       ushort* __restrict__ Wt, ushort* __restrict__ Wot,
                       const float* __restrict__ bq, const float* __restrict__ bk,
                       const float* __restrict__ bv, float* __restrict__ bqkv) {
    __shared__ float tile[64][65];
    const int bid = blockIdx.x, t = threadIdx.x;
    if (bid < 6144) {                      // x -> bf16
        size_t i = ((size_t)bid * 256 + t) * 8;
        float4 v0 = *(const float4*)(x + i);
        float4 v1 = *(const float4*)(x + i + 4);
        shortx8 o;
        o[0] = (short)f2b(v0.x); o[1] = (short)f2b(v0.y);
        o[2] = (short)f2b(v0.z); o[3] = (short)f2b(v0.w);
        o[4] = (short)f2b(v1.x); o[5] = (short)f2b(v1.y);
        o[6] = (short)f2b(v1.z); o[7] = (short)f2b(v1.w);
        *(shortx8*)(xb + i) = o;
    } else if (bid < 6720) {               // W [in][out] fp32 -> [out][in] bf16
        int pid = bid - 6144;
        int zi = pid / 144, rem = pid % 144;
        const float* W = (zi == 0) ? Wq : (zi == 1) ? Wk : (zi == 2) ? Wv : Wo;
        const int i0 = (rem / 12) * 64, j0 = (rem % 12) * 64;
        const int c = t & 63, r4 = t >> 6;
        for (int rr = r4; rr < 64; rr += 4)
            tile[rr][c] = W[(size_t)(i0 + rr) * 768 + j0 + c];
        __syncthreads();
        ushort* dst = (zi < 3) ? (Wt + (size_t)(zi * 768) * 768) : Wot;
        for (int jj = r4; jj < 64; jj += 4)
            dst[(size_t)(j0 + jj) * 768 + i0 + c] = f2b(tile[c][jj]);
    } else {                               // bias pack
        int j = (bid - 6720) * 256 + t;
        if (j < 2304) {
            const float* src = (j < 768) ? bq : (j < 1536) ? bk : bv;
            bqkv[j] = src[j % 768];
        }
    }
}

// ---------------- main GEMM: BK=64, XOR chunk swizzle + locality swizzle ------
// LDS logical As[row][k0..63]; element (r,k) at r*64 + ((k>>3)^(r&7))*8 + (k&7).
// Staging: glds16 #i covers rows +i*8..+i*8+8, lane -> (row=lane>>3, slot=lane&7),
// source column permuted per lane so coalescing (full 128B rows) is preserved.
// Block-index swizzle: two bijective layers on the linear dispatch id:
//   1. XCD chunking (m204): wg = (lin&7)*(NWG/8) + (lin>>3) -> each XCD's L2
//      holds a stable contiguous slice of logical tiles.
//   2. Super-tile traversal: band of 8 m-blocks (fast) x all n-blocks (slow);
//      8 A-panels (1.6 MB) stay L2-hot while 196 KB B panels stream.
template <int MODE>
__global__ __launch_bounds__(256, 4) void k_gemm(
    const ushort* __restrict__ A, const ushort* __restrict__ Bt,
    const float* __restrict__ bias, void* __restrict__ Cout, int Ncols) {
    constexpr int K = 768;
    constexpr int GY = (MODE == 0) ? 18 : 6;   // grid.y (must match launch)
    constexpr int NWG = 128 * GY;
    __shared__ ushort As[128 * 64];
    __shared__ ushort Bs[128 * 64];

    const int lin  = blockIdx.y * 128 + blockIdx.x;       // dispatch order
    const int wg   = (lin & 7) * (NWG / 8) + (lin >> 3);  // XCD-contiguous
    const int band = wg / (8 * GY);                       // super-row of 8 m-blocks
    const int rem  = wg % (8 * GY);
    const int m0 = (band * 8 + (rem & 7)) * 128;
    const int n0 = (rem >> 3) * 128;

    const int tid = threadIdx.x;
    const int w = tid >> 6, lane = tid & 63;

    const int lr = lane >> 3;                    // row within 8-row slab
    const int lc = ((lane & 7) ^ lr) * 8;        // swizzled source chunk
    const ushort* aBase = A  + (size_t)(m0 + w * 32 + lr) * K + lc;
    const ushort* bBase = Bt + (size_t)(n0 + w * 32 + lr) * K + lc;
    ushort* aL = As + (w * 32) * 64;             // wave-uniform LDS bases
    ushort* bL = Bs + (w * 32) * 64;

    const int rBase = (w >> 1) * 64;
    const int nBase = (w & 1) * 64;
    const int fr = lane & 15;
    const int q4 = lane >> 4;

    floatx4 acc[4][4] = {};

    for (int k0 = 0; k0 < K; k0 += 64) {
#pragma unroll
        for (int i = 0; i < 4; ++i) glds16(aBase + i * (8 * K) + k0, aL + i * (8 * 64));
#pragma unroll
        for (int i = 0; i < 4; ++i) glds16(bBase + i * (8 * K) + k0, bL + i * (8 * 64));
        __syncthreads();
#pragma unroll
        for (int kc = 0; kc < 2; ++kc) {
            const int off = ((kc * 4 + q4) ^ (fr & 7)) * 8;
            bf16x8 af[4], bf[4];
#pragma unroll
            for (int rt = 0; rt < 4; ++rt)
                af[rt] = *(const bf16x8*)(As + (rBase + rt * 16 + fr) * 64 + off);
#pragma unroll
            for (int nt = 0; nt < 4; ++nt)
                bf[nt] = *(const bf16x8*)(Bs + (nBase + nt * 16 + fr) * 64 + off);
#pragma unroll
            for (int rt = 0; rt < 4; ++rt)
#pragma unroll
                for (int nt = 0; nt < 4; ++nt)
                    acc[rt][nt] = mfma_bf16(af[rt], bf[nt], acc[rt][nt]);
        }
        __syncthreads();
    }

#pragma unroll
    for (int rt = 0; rt < 4; ++rt) {
#pragma unroll
        for (int nt = 0; nt < 4; ++nt) {
#pragma unroll
            for (int r = 0; r < 4; ++r) {
                int m = m0 + rBase + rt * 16 + q4 * 4 + r;
                int n = n0 + nBase + nt * 16 + fr;
                float v = acc[rt][nt][r] + bias[n];
                if (MODE == 0) {
                    if (n < 1536) v = (v > 0.f) ? (v + 1.f) : __expf(v);  // phi
                    ((ushort*)Cout)[(size_t)m * Ncols + n] = f2b(v);
                } else {
                    ((float*)Cout)[(size_t)m * Ncols + n] = v;
                }
            }
        }
    }
}

// ---------------- kv + ksum via MFMA (stride 70: conflict-free reads) ---------
__global__ __launch_bounds__(256) void k_kv(const ushort* __restrict__ QKV,
                                            float* __restrict__ kvp) {
    const int bh = blockIdx.x, s = blockIdx.y;
    const int bb = bh / 12, head = bh % 12;
    __shared__ ushort kS[64 * 70];
    __shared__ ushort vS[64 * 70];
    const int t = threadIdx.x, w = t >> 6, lane = t & 63;
    const int fr = lane & 15, fk = (lane >> 4) * 8;

    floatx4 acc[5] = {};
    const int n_ld = t >> 2, c16 = (t & 3) * 16;
    const ushort* base = QKV + (size_t)(bb * 4096 + s * 512) * 2304 + 768 + head * 64 + c16;

    for (int rr = 0; rr < 8; ++rr) {
        if (rr) __syncthreads();
        {
            const ushort* kp = base + (size_t)(rr * 64 + n_ld) * 2304;
            union { shortx8 v8; shortx2 v2[4]; } k0, k1, v0, v1;
            k0.v8 = *(const shortx8*)(kp);
            k1.v8 = *(const shortx8*)(kp + 8);
            v0.v8 = *(const shortx8*)(kp + 768);
            v1.v8 = *(const shortx8*)(kp + 776);
            ushort* kd = kS + n_ld * 70 + c16;
            ushort* vd = vS + n_ld * 70 + c16;
#pragma unroll
            for (int i = 0; i < 4; ++i) {
                *(shortx2*)(kd + 2 * i)     = k0.v2[i];
                *(shortx2*)(kd + 8 + 2 * i) = k1.v2[i];
                *(shortx2*)(vd + 2 * i)     = v0.v2[i];
                *(shortx2*)(vd + 8 + 2 * i) = v1.v2[i];
            }
        }
        __syncthreads();
#pragma unroll
        for (int kl = 0; kl < 64; kl += 32) {
            union { bf16x8 v; ushort u[8]; } bfr, afr[4];
#pragma unroll
            for (int i = 0; i < 8; ++i) {
                int n = kl + fk + i;
                bfr.u[i] = kS[n * 70 + w * 16 + fr];
#pragma unroll
                for (int mt = 0; mt < 4; ++mt)
                    afr[mt].u[i] = vS[n * 70 + mt * 16 + fr];
            }
            union { bf16x8 v; ushort u[8]; } ones;
            ushort ov = (fr == 0) ? (ushort)0x3F80 : (ushort)0;
#pragma unroll
            for (int i = 0; i < 8; ++i) ones.u[i] = ov;
#pragma unroll
            for (int mt = 0; mt < 4; ++mt)
                acc[mt] = mfma_bf16(afr[mt].v, bfr.v, acc[mt]);
            acc[4] = mfma_bf16(ones.v, bfr.v, acc[4]);
        }
    }

    float* dst = kvp + ((size_t)bh * 8 + s) * (65 * 64);
#pragma unroll
    for (int mt = 0; mt < 4; ++mt)
#pragma unroll
        for (int r = 0; r < 4; ++r)
            dst[(mt * 16 + (lane >> 4) * 4 + r) * 64 + w * 16 + fr] = acc[mt][r];
    if (lane < 16) dst[64 * 64 + w * 16 + lane] = acc[4][0];
}

// reduce 8 partials, emit bf16: kvb [48][65][64]
__global__ void k_kvred(const float* __restrict__ kvp, ushort* __restrict__ kvb) {
    int t4 = (blockIdx.x * 256 + threadIdx.x) * 4;   // 195*256*4 == 199680
    int bh = t4 / 4160, rem = t4 % 4160;
    const float* p = kvp + (size_t)bh * 8 * 4160 + rem;
    float4 sum = {0.f, 0.f, 0.f, 0.f};
    for (int i = 0; i < 8; ++i) {
        float4 a = *(const float4*)(p + (size_t)i * 4160);
        sum.x += a.x; sum.y += a.y; sum.z += a.z; sum.w += a.w;
    }
    shortx4 o;
    o[0] = (short)f2b(sum.x); o[1] = (short)f2b(sum.y);
    o[2] = (short)f2b(sum.z); o[3] = (short)f2b(sum.w);
    *(shortx4*)(kvb + t4) = o;
}

// ---------------- num + z + normed (MFMA) ----------------
__global__ __launch_bounds__(256) void k_num(const ushort* __restrict__ QKV,
                                             const ushort* __restrict__ kvb,
                                             ushort* __restrict__ normed) {
    const int bh = blockIdx.x, l0 = blockIdx.y * 128;
    const int bb = bh / 12, head = bh % 12;
    __shared__ ushort qsh[128 * 72];
    __shared__ ushort kvT[80 * 72];
    __shared__ float dnm[128];
    const int t = threadIdx.x, w = t >> 6, lane = t & 63;

    {
        const ushort* kvbb = kvb + (size_t)bh * 4160;
        int c8 = (t & 7) * 8;
        for (int r0 = (t >> 3); r0 < 65; r0 += 32)
            *(shortx8*)(kvT + r0 * 72 + c8) = *(const shortx8*)(kvbb + r0 * 64 + c8);
    }
    for (int idx = t; idx < 15 * 72; idx += 256) kvT[65 * 72 + idx] = 0;

    const ushort* qg = QKV + (size_t)(bb * 4096 + l0) * 2304 + head * 64;
    {
        int row = t >> 3, c8 = (t & 7) * 8;
#pragma unroll
        for (int i = 0; i < 4; ++i) {
            shortx8 v = *(const shortx8*)(qg + (size_t)(i * 32 + row) * 2304 + c8);
            *(shortx8*)(qsh + (i * 32 + row) * 72 + c8) = v;
        }
    }
    __syncthreads();

    const int fr = lane & 15, fk = (lane >> 4) * 8;
    floatx4 acc[2][5] = {};
#pragma unroll
    for (int kc = 0; kc < 2; ++kc) {
        bf16x8 a[2], b[5];
#pragma unroll
        for (int rt = 0; rt < 2; ++rt)
            a[rt] = *(const bf16x8*)(qsh + (w * 32 + rt * 16 + fr) * 72 + kc * 32 + fk);
#pragma unroll
        for (int nt = 0; nt < 5; ++nt)
            b[nt] = *(const bf16x8*)(kvT + (nt * 16 + fr) * 72 + kc * 32 + fk);
#pragma unroll
        for (int rt = 0; rt < 2; ++rt)
#pragma unroll
            for (int nt = 0; nt < 5; ++nt)
                acc[rt][nt] = mfma_bf16(a[rt], b[nt], acc[rt][nt]);
    }
    if (fr == 0) {
#pragma unroll
        for (int rt = 0; rt < 2; ++rt)
#pragma unroll
            for (int r = 0; r < 4; ++r)
                dnm[w * 32 + rt * 16 + (lane >> 4) * 4 + r] = acc[rt][4][r];
    }
    __syncthreads();
#pragma unroll
    for (int rt = 0; rt < 2; ++rt) {
#pragma unroll
        for (int r = 0; r < 4; ++r) {
            int ml = w * 32 + rt * 16 + (lane >> 4) * 4 + r;
            float z = 1.f / dnm[ml];
            size_t base = (size_t)(bb * 4096 + l0 + ml) * 768 + head * 64;
#pragma unroll
            for (int nt = 0; nt < 4; ++nt)
                normed[base + nt * 16 + fr] = f2b(acc[rt][nt][r] * z);
        }
    }
}

// ---------------- launch ----------------
extern "C" void kernel_launch(void* const* d_in, const int* in_sizes, int n_in,
                              void* d_out, int out_size, void* d_ws, size_t ws_size,
                              hipStream_t stream) {
    const float* x  = (const float*)d_in[0];
    const float* Wq = (const float*)d_in[1];
    const float* bq = (const float*)d_in[2];
    const float* Wk = (const float*)d_in[3];
    const float* bk = (const float*)d_in[4];
    const float* Wv = (const float*)d_in[5];
    const float* bv = (const float*)d_in[6];
    const float* Wo = (const float*)d_in[7];
    const float* bo = (const float*)d_in[8];

    char* ws = (char*)d_ws;
    ushort* Xb   = (ushort*)(ws);                 // 25,165,824 B (reused as normed)
    ushort* Wt   = (ushort*)(ws + 25165824);      //  3,538,944 B
    ushort* Wot  = (ushort*)(ws + 28704768);      //  1,179,648 B
    float*  bqkv = (float*)(ws + 29884416);       //      9,216 B
    ushort* QKV  = (ushort*)(ws + 29893632);      // 75,497,472 B
    float*  kvp  = (float*)(ws + 105391104);      //  6,389,760 B
    ushort* kvb  = (ushort*)(ws + 111780864);     //    399,360 B
    ushort* normed = Xb;

    k_prep <<<dim3(6729),      256, 0, stream>>>(x, Xb, Wq, Wk, Wv, Wo, Wt, Wot,
                                                 bq, bk, bv, bqkv);
    k_gemm<0><<<dim3(128, 18), 256, 0, stream>>>(Xb, Wt, bqkv, (void*)QKV, 2304);
    k_kv   <<<dim3(48, 8),     256, 0, stream>>>(QKV, kvp);
    k_kvred<<<dim3(195),       256, 0, stream>>>(kvp, kvb);
    k_num  <<<dim3(48, 32),    256, 0, stream>>>(QKV, kvb, normed);
    k_gemm<1><<<dim3(128, 6),  256, 0, stream>>>(normed, Wot, bo, d_out, 768);
}